// Round 16
// baseline (42.848 us; speedup 1.0000x reference)
//
#include <hip/hip_runtime.h>
#include <hip/hip_bf16.h>
#include <stdint.h>

// SpectralPooling: x (4,32,64,64,64) f32 -> out (4,32,32,32,32) f32.
// Separable: out[bc,k,j,l] = sum_{d,h,w} A[k,d]A[j,h]A[l,w] x[bc,d,h,w],
// A = (32x64) fused DCT64->crop32->IDCT32 matrix.
// R16: k_hw = R15-exact. k_d rewritten LDS-tiled: dense uint4 staging of the
//      [64][256] w1b tile (one latency exposure) + packed k-pair v_pk_fma_f32
//      from the LDS tile. Tables remain compile-time __constant__.
//
// MFMA conventions (mfma_f32_16x16x32_bf16), HW-verified by R3-R15 passing:
//   A-op: lane m = lane&15, k = 8*(lane>>4)+jj ; B-op same map (k-perm cancels)
//   C/D : col = lane&15, row = 4*(lane>>4)+reg

typedef __attribute__((ext_vector_type(4))) float f32x4;
typedef __attribute__((ext_vector_type(2))) float f32x2;
typedef __attribute__((ext_vector_type(8))) short bf16x8;

union U16x8 { uint4 q; bf16x8 v; uint32_t w[4]; };

// pair f32 -> packed bf16 (RNE) ; compiles to v_cvt_pk_bf16_f32
__device__ __forceinline__ uint32_t pk(float a, float b) {
    union { __hip_bfloat162 h; uint32_t u; } c;
    c.h = __float22bfloat162_rn(make_float2(a, b));
    return c.u;
}

// ================= compile-time tables =================
struct Tabs {
    float At[2048];   // At[d*32+i] = A[i][d]           (k_d, wave-uniform s_load)
    float Ff[2048];   // Ff[((tt*2+kt)*64+lane)*8+jj] = A[tt*16+(lane&15)][kt*32+8*(lane>>4)+jj]
};

constexpr double kPI = 3.14159265358979323846;

constexpr double csqrt(double v) {
    double g = v;
    for (int i = 0; i < 64; ++i) g = 0.5 * (g + v / g);
    return g;
}

constexpr Tabs make_tabs() {
    // ct[n] = cos(pi*n/128), n in [0,256): quadrant-reduce + 12-term Taylor
    double ct[256] = {};
    for (int n = 0; n < 256; ++n) {
        int m = n;
        if (m > 128) m = 256 - m;
        double sgn = 1.0;
        if (m > 64) { m = 128 - m; sgn = -1.0; }
        double x = kPI * (double)m / 128.0;
        double x2 = x * x, term = 1.0, sum = 1.0;
        for (int i = 1; i <= 12; ++i) {
            term *= -x2 / (double)((2 * i - 1) * (2 * i));
            sum += term;
        }
        ct[n] = sgn * sum;
    }
    // w[k] = s32(k)*s64(k)
    double w[32] = {};
    {
        double sA0 = csqrt(1.0 / 32.0), sA = csqrt(2.0 / 32.0);
        double sB0 = csqrt(1.0 / 64.0), sB = csqrt(2.0 / 64.0);
        for (int k = 0; k < 32; ++k)
            w[k] = (k == 0 ? sA0 : sA) * (k == 0 ? sB0 : sB);
    }
    Tabs T{};
    // At[d*32+i] = A[i][d] = sum_k w[k] cos(pi(2i+1)k/64) cos(pi(2d+1)k/128)
    for (int i = 0; i < 32; ++i) {
        int a2 = 2 * i + 1;
        for (int d = 0; d < 64; ++d) {
            int b2 = 2 * d + 1;
            double acc = 0.0;
            for (int k = 0; k < 32; ++k) {
                int n1 = (2 * (a2 * k)) & 255;   // cos(pi*(a2 k)/64) = ct[(2 a2 k) mod 256]
                int n2 = (b2 * k) & 255;         // cos(pi*(b2 k)/128)
                acc += w[k] * ct[n1] * ct[n2];
            }
            T.At[d * 32 + i] = (float)acc;
        }
    }
    // Ff frag table (f32; kernel converts to bf16 with v_cvt_pk RNE)
    for (int tt = 0; tt < 2; ++tt)
        for (int kt = 0; kt < 2; ++kt)
            for (int lane = 0; lane < 64; ++lane)
                for (int jj = 0; jj < 8; ++jj) {
                    int row = tt * 16 + (lane & 15);
                    int col = kt * 32 + ((lane >> 4) << 3) + jj;
                    T.Ff[((tt * 2 + kt) * 64 + lane) * 8 + jj] = T.At[col * 32 + row];
                }
    return T;
}

constexpr Tabs kTabs = make_tabs();
__constant__ Tabs g_tabs = kTabs;

// ---- k_hw: R15-exact. 4 waves/block, one slab per wave, wave-private LDS. ----
__global__ __launch_bounds__(256, 4) void k_hw(const float* __restrict__ x,
                                               unsigned short* __restrict__ w1b) {
    __shared__ unsigned short Ut[4][2048];   // per-wave Ut[l][h] bf16, XOR-swizzled

    const int t = threadIdx.x;
    const int wv = t >> 6, ln = t & 63;
    const int lm = ln & 15, lg = ln >> 4;
    const size_t slab = (size_t)blockIdx.x * 4 + wv;

    // constant B-operand frags (f32 table -> pk to bf16, identical RNE values)
    bf16x8 Ff[2][2];
    #pragma unroll
    for (int tt = 0; tt < 2; ++tt)
        #pragma unroll
        for (int kt = 0; kt < 2; ++kt) {
            const float4* fp4 = (const float4*)(g_tabs.Ff + ((tt * 2 + kt) * 64 + ln) * 8);
            float4 fa = fp4[0], fb = fp4[1];
            U16x8 u;
            u.w[0] = pk(fa.x, fa.y);
            u.w[1] = pk(fa.z, fa.w);
            u.w[2] = pk(fb.x, fb.y);
            u.w[3] = pk(fb.z, fb.w);
            Ff[tt][kt] = u.v;
        }

    // ---- issue all 16 x-loads up front ----
    const float* xs = x + slab * 4096;
    uint4 raw[16];
    #pragma unroll
    for (int mt = 0; mt < 4; ++mt)
        #pragma unroll
        for (int kt = 0; kt < 2; ++kt) {
            const uint4* p = (const uint4*)(xs + (mt * 16 + lm) * 64 + kt * 32 + (lg << 3));
            raw[(mt * 2 + kt) * 2 + 0] = p[0];
            raw[(mt * 2 + kt) * 2 + 1] = p[1];
        }

    // ---- stage B: U[h][l] = sum_w X[h][w] * A[l][w] ----
    f32x4 accu[4][2];
    #pragma unroll
    for (int mt = 0; mt < 4; ++mt)
        #pragma unroll
        for (int nt = 0; nt < 2; ++nt)
            accu[mt][nt] = (f32x4){0.f, 0.f, 0.f, 0.f};

    #pragma unroll
    for (int mt = 0; mt < 4; ++mt) {
        #pragma unroll
        for (int kt = 0; kt < 2; ++kt) {
            const float* f0 = (const float*)&raw[(mt * 2 + kt) * 2];
            U16x8 xf;
            #pragma unroll
            for (int e = 0; e < 4; ++e)
                xf.w[e] = pk(f0[2 * e], f0[2 * e + 1]);   // v_cvt_pk_bf16_f32
            #pragma unroll
            for (int nt = 0; nt < 2; ++nt)
                accu[mt][nt] = __builtin_amdgcn_mfma_f32_16x16x32_bf16(
                    xf.v, Ff[nt][kt], accu[mt][nt], 0, 0, 0);
        }
    }

    // ---- transpose U -> Ut[l][h] (bf16, XOR-swizzled), wave-private ----
    unsigned short* ut = Ut[wv];
    #pragma unroll
    for (int mt = 0; mt < 4; ++mt)
        #pragma unroll
        for (int nt = 0; nt < 2; ++nt) {
            int lo = nt * 16 + lm;               // Ut row (= l)
            int h0 = mt * 16 + (lg << 2);        // 4 consecutive h
            uint32_t w0 = pk(accu[mt][nt][0], accu[mt][nt][1]);
            uint32_t w1v = pk(accu[mt][nt][2], accu[mt][nt][3]);
            uint32_t byte = (uint32_t)(lo * 128 + 2 * h0);
            byte ^= (uint32_t)((lo & 7) << 4);   // bank swizzle
            *(uint2*)((char*)ut + byte) = make_uint2(w0, w1v);
        }
    __builtin_amdgcn_wave_barrier();

    // ---- stage C: O^T[l][j] = sum_h Ut[l][h] * A[j][h] ----
    f32x4 acco[2][2];
    #pragma unroll
    for (int mt = 0; mt < 2; ++mt)
        #pragma unroll
        for (int nt = 0; nt < 2; ++nt)
            acco[mt][nt] = (f32x4){0.f, 0.f, 0.f, 0.f};

    #pragma unroll
    for (int mt = 0; mt < 2; ++mt) {
        #pragma unroll
        for (int kt = 0; kt < 2; ++kt) {
            int lo = mt * 16 + lm;
            uint32_t byte = (uint32_t)(lo * 128 + kt * 64 + (lg << 4));
            byte ^= (uint32_t)((lo & 7) << 4);
            bf16x8 uf = *(const bf16x8*)((const char*)ut + byte);  // ds_read_b128
            #pragma unroll
            for (int nt = 0; nt < 2; ++nt)
                acco[mt][nt] = __builtin_amdgcn_mfma_f32_16x16x32_bf16(
                    uf, Ff[nt][kt], acco[mt][nt], 0, 0, 0);
        }
    }

    // ---- direct packed store: lane owns 4 consecutive l per (mt,nt) ----
    #pragma unroll
    for (int mt = 0; mt < 2; ++mt)
        #pragma unroll
        for (int nt = 0; nt < 2; ++nt) {
            uint32_t u0 = pk(acco[mt][nt][0], acco[mt][nt][1]);
            uint32_t u1 = pk(acco[mt][nt][2], acco[mt][nt][3]);
            int j  = nt * 16 + lm;
            int l0 = mt * 16 + (lg << 2);
            *(uint2*)(w1b + slab * 1024 + j * 32 + l0) = make_uint2(u0, u1);
        }
}

// ---- k_d: LDS-tiled. grid = 128 bc x 2 kh x 4 q = 1024 blocks ----
// Stage [64 d][256 p] tile (32 KiB) with 8 dense uint4 loads/thread (one
// latency exposure), then contract with packed k-pair FMA from LDS.
__global__ __launch_bounds__(256) void k_d(const unsigned short* __restrict__ w1b,
                                           float* __restrict__ out) {
    __shared__ unsigned short T[64 * 256];   // [d][p-local], 32 KiB

    const int t = threadIdx.x;
    const int bc = blockIdx.x >> 3;
    const int kh = (blockIdx.x >> 2) & 1;
    const int q  = blockIdx.x & 3;

    // ---- stage: 2048 uint4 chunks, thread t takes 8 (all independent) ----
    const uint4* src = (const uint4*)(w1b + (size_t)bc * 65536 + q * 256);
    #pragma unroll
    for (int i = 0; i < 8; ++i) {
        int c = i * 256 + t;              // 0..2047
        int d = c >> 5;                   // 32 uint4 per 512-B tile row
        int po = (c & 31) * 8;            // ushort offset within row
        uint4 v = src[(size_t)d * 128 + (c & 31)];   // global row stride 2048 B
        *(uint4*)(T + d * 256 + po) = v;
    }
    __syncthreads();

    // ---- contract: acc over 16 k (kh half) as 8 packed pairs ----
    f32x2 acc2[8];
    #pragma unroll
    for (int k = 0; k < 8; ++k) acc2[k] = (f32x2){0.f, 0.f};

    #pragma unroll 8
    for (int d = 0; d < 64; ++d) {
        uint32_t u = (uint32_t)T[d * 256 + t];       // 2-way bank = free
        float v = __uint_as_float(u << 16);          // bf16 -> f32
        f32x2 vv = {v, v};
        const f32x2* ap = (const f32x2*)(g_tabs.At + d * 32 + kh * 16);  // s_load
        #pragma unroll
        for (int k = 0; k < 8; ++k)
            acc2[k] += ap[k] * vv;                   // v_pk_fma_f32
    }

    float* dst = out + (size_t)bc * 32768 + (size_t)kh * 16384 + q * 256 + t;
    #pragma unroll
    for (int k = 0; k < 8; ++k) {
        dst[(2 * k) * 1024]     = acc2[k].x;
        dst[(2 * k + 1) * 1024] = acc2[k].y;
    }
}

extern "C" void kernel_launch(void* const* d_in, const int* in_sizes, int n_in,
                              void* d_out, int out_size, void* d_ws, size_t ws_size,
                              hipStream_t stream) {
    const float* x = (const float*)d_in[0];
    float* out = (float*)d_out;
    unsigned short* w1b = (unsigned short*)d_ws;   // 16 MiB (bf16)

    k_hw<<<2048, 256, 0, stream>>>(x, w1b);
    k_d<<<1024, 256, 0, stream>>>(w1b, out);
}

// Round 17
// 40.828 us; speedup vs baseline: 1.0495x; 1.0495x over previous
//
#include <hip/hip_runtime.h>
#include <hip/hip_bf16.h>
#include <stdint.h>

// SpectralPooling: x (4,32,64,64,64) f32 -> out (4,32,32,32,32) f32.
// Separable: out[bc,k,j,l] = sum_{d,h,w} A[k,d]A[j,h]A[l,w] x[bc,d,h,w],
// A = (32x64) fused DCT64->crop32->IDCT32 matrix.
// R17 = R15-exact restore (best measured: 40.78 us).
//   Tables: compile-time constexpr -> __constant__ (no build kernel, no H2D).
//   k_hw: MFMA bf16, 4 waves/block, slab-per-wave, 16 up-front loads,
//         cvt_pk conversions, XOR-swizzled wave-private LDS transpose,
//         direct packed store.  k_d: R4-exact geometry (1024 blocks).
//
// MFMA conventions (mfma_f32_16x16x32_bf16), HW-verified by R3-R16 passing:
//   A-op: lane m = lane&15, k = 8*(lane>>4)+jj ; B-op same map (k-perm cancels)
//   C/D : col = lane&15, row = 4*(lane>>4)+reg

typedef __attribute__((ext_vector_type(4))) float f32x4;
typedef __attribute__((ext_vector_type(8))) short bf16x8;

union U16x8 { uint4 q; bf16x8 v; uint32_t w[4]; };

// pair f32 -> packed bf16 (RNE) ; compiles to v_cvt_pk_bf16_f32
__device__ __forceinline__ uint32_t pk(float a, float b) {
    union { __hip_bfloat162 h; uint32_t u; } c;
    c.h = __float22bfloat162_rn(make_float2(a, b));
    return c.u;
}

// ================= compile-time tables =================
struct Tabs {
    float At[2048];   // At[d*32+i] = A[i][d]           (k_d, wave-uniform s_load)
    float Ff[2048];   // Ff[((tt*2+kt)*64+lane)*8+jj] = A[tt*16+(lane&15)][kt*32+8*(lane>>4)+jj]
};

constexpr double kPI = 3.14159265358979323846;

constexpr double csqrt(double v) {
    double g = v;
    for (int i = 0; i < 64; ++i) g = 0.5 * (g + v / g);
    return g;
}

constexpr Tabs make_tabs() {
    // ct[n] = cos(pi*n/128), n in [0,256): quadrant-reduce + 12-term Taylor
    double ct[256] = {};
    for (int n = 0; n < 256; ++n) {
        int m = n;
        if (m > 128) m = 256 - m;
        double sgn = 1.0;
        if (m > 64) { m = 128 - m; sgn = -1.0; }
        double x = kPI * (double)m / 128.0;
        double x2 = x * x, term = 1.0, sum = 1.0;
        for (int i = 1; i <= 12; ++i) {
            term *= -x2 / (double)((2 * i - 1) * (2 * i));
            sum += term;
        }
        ct[n] = sgn * sum;
    }
    // w[k] = s32(k)*s64(k)
    double w[32] = {};
    {
        double sA0 = csqrt(1.0 / 32.0), sA = csqrt(2.0 / 32.0);
        double sB0 = csqrt(1.0 / 64.0), sB = csqrt(2.0 / 64.0);
        for (int k = 0; k < 32; ++k)
            w[k] = (k == 0 ? sA0 : sA) * (k == 0 ? sB0 : sB);
    }
    Tabs T{};
    // At[d*32+i] = A[i][d] = sum_k w[k] cos(pi(2i+1)k/64) cos(pi(2d+1)k/128)
    for (int i = 0; i < 32; ++i) {
        int a2 = 2 * i + 1;
        for (int d = 0; d < 64; ++d) {
            int b2 = 2 * d + 1;
            double acc = 0.0;
            for (int k = 0; k < 32; ++k) {
                int n1 = (2 * (a2 * k)) & 255;   // cos(pi*(a2 k)/64) = ct[(2 a2 k) mod 256]
                int n2 = (b2 * k) & 255;         // cos(pi*(b2 k)/128)
                acc += w[k] * ct[n1] * ct[n2];
            }
            T.At[d * 32 + i] = (float)acc;
        }
    }
    // Ff frag table (f32; kernel converts to bf16 with v_cvt_pk RNE)
    for (int tt = 0; tt < 2; ++tt)
        for (int kt = 0; kt < 2; ++kt)
            for (int lane = 0; lane < 64; ++lane)
                for (int jj = 0; jj < 8; ++jj) {
                    int row = tt * 16 + (lane & 15);
                    int col = kt * 32 + ((lane >> 4) << 3) + jj;
                    T.Ff[((tt * 2 + kt) * 64 + lane) * 8 + jj] = T.At[col * 32 + row];
                }
    return T;
}

constexpr Tabs kTabs = make_tabs();
__constant__ Tabs g_tabs = kTabs;

// ---- k_hw: 4 waves/block, one slab per wave, wave-private LDS only.
// launch_bounds(256,4): cap 128 VGPR -> 4 waves/SIMD (16 waves/CU).
__global__ __launch_bounds__(256, 4) void k_hw(const float* __restrict__ x,
                                               unsigned short* __restrict__ w1b) {
    __shared__ unsigned short Ut[4][2048];   // per-wave Ut[l][h] bf16, XOR-swizzled

    const int t = threadIdx.x;
    const int wv = t >> 6, ln = t & 63;
    const int lm = ln & 15, lg = ln >> 4;
    const size_t slab = (size_t)blockIdx.x * 4 + wv;

    // constant B-operand frags (f32 table -> pk to bf16, identical RNE values)
    bf16x8 Ff[2][2];
    #pragma unroll
    for (int tt = 0; tt < 2; ++tt)
        #pragma unroll
        for (int kt = 0; kt < 2; ++kt) {
            const float4* fp4 = (const float4*)(g_tabs.Ff + ((tt * 2 + kt) * 64 + ln) * 8);
            float4 fa = fp4[0], fb = fp4[1];
            U16x8 u;
            u.w[0] = pk(fa.x, fa.y);
            u.w[1] = pk(fa.z, fa.w);
            u.w[2] = pk(fb.x, fb.y);
            u.w[3] = pk(fb.z, fb.w);
            Ff[tt][kt] = u.v;
        }

    // ---- issue all 16 x-loads up front ----
    const float* xs = x + slab * 4096;
    uint4 raw[16];
    #pragma unroll
    for (int mt = 0; mt < 4; ++mt)
        #pragma unroll
        for (int kt = 0; kt < 2; ++kt) {
            const uint4* p = (const uint4*)(xs + (mt * 16 + lm) * 64 + kt * 32 + (lg << 3));
            raw[(mt * 2 + kt) * 2 + 0] = p[0];
            raw[(mt * 2 + kt) * 2 + 1] = p[1];
        }

    // ---- stage B: U[h][l] = sum_w X[h][w] * A[l][w] ----
    f32x4 accu[4][2];
    #pragma unroll
    for (int mt = 0; mt < 4; ++mt)
        #pragma unroll
        for (int nt = 0; nt < 2; ++nt)
            accu[mt][nt] = (f32x4){0.f, 0.f, 0.f, 0.f};

    #pragma unroll
    for (int mt = 0; mt < 4; ++mt) {
        #pragma unroll
        for (int kt = 0; kt < 2; ++kt) {
            const float* f0 = (const float*)&raw[(mt * 2 + kt) * 2];
            U16x8 xf;
            #pragma unroll
            for (int e = 0; e < 4; ++e)
                xf.w[e] = pk(f0[2 * e], f0[2 * e + 1]);   // v_cvt_pk_bf16_f32
            #pragma unroll
            for (int nt = 0; nt < 2; ++nt)
                accu[mt][nt] = __builtin_amdgcn_mfma_f32_16x16x32_bf16(
                    xf.v, Ff[nt][kt], accu[mt][nt], 0, 0, 0);
        }
    }

    // ---- transpose U -> Ut[l][h] (bf16, XOR-swizzled), wave-private ----
    unsigned short* ut = Ut[wv];
    #pragma unroll
    for (int mt = 0; mt < 4; ++mt)
        #pragma unroll
        for (int nt = 0; nt < 2; ++nt) {
            int lo = nt * 16 + lm;               // Ut row (= l)
            int h0 = mt * 16 + (lg << 2);        // 4 consecutive h
            uint32_t w0 = pk(accu[mt][nt][0], accu[mt][nt][1]);
            uint32_t w1v = pk(accu[mt][nt][2], accu[mt][nt][3]);
            uint32_t byte = (uint32_t)(lo * 128 + 2 * h0);
            byte ^= (uint32_t)((lo & 7) << 4);   // bank swizzle
            *(uint2*)((char*)ut + byte) = make_uint2(w0, w1v);
        }
    __builtin_amdgcn_wave_barrier();

    // ---- stage C: O^T[l][j] = sum_h Ut[l][h] * A[j][h] ----
    f32x4 acco[2][2];
    #pragma unroll
    for (int mt = 0; mt < 2; ++mt)
        #pragma unroll
        for (int nt = 0; nt < 2; ++nt)
            acco[mt][nt] = (f32x4){0.f, 0.f, 0.f, 0.f};

    #pragma unroll
    for (int mt = 0; mt < 2; ++mt) {
        #pragma unroll
        for (int kt = 0; kt < 2; ++kt) {
            int lo = mt * 16 + lm;
            uint32_t byte = (uint32_t)(lo * 128 + kt * 64 + (lg << 4));
            byte ^= (uint32_t)((lo & 7) << 4);
            bf16x8 uf = *(const bf16x8*)((const char*)ut + byte);  // ds_read_b128
            #pragma unroll
            for (int nt = 0; nt < 2; ++nt)
                acco[mt][nt] = __builtin_amdgcn_mfma_f32_16x16x32_bf16(
                    uf, Ff[nt][kt], acco[mt][nt], 0, 0, 0);
        }
    }

    // ---- direct packed store: lane owns 4 consecutive l per (mt,nt) ----
    #pragma unroll
    for (int mt = 0; mt < 2; ++mt)
        #pragma unroll
        for (int nt = 0; nt < 2; ++nt) {
            uint32_t u0 = pk(acco[mt][nt][0], acco[mt][nt][1]);
            uint32_t u1 = pk(acco[mt][nt][2], acco[mt][nt][3]);
            int j  = nt * 16 + lm;
            int l0 = mt * 16 + (lg << 2);
            *(uint2*)(w1b + slab * 1024 + j * 32 + l0) = make_uint2(u0, u1);
        }
}

// ---- k_d: R4-exact (measured-best). grid = 128 bc x 2 kh x 4 q = 1024 ----
// out[bc][kh*16+kk][p] = sum_d At[d][kh*16+kk] * w1b[bc][d][p]
__global__ __launch_bounds__(256) void k_d(const unsigned short* __restrict__ w1b,
                                           float* __restrict__ out) {
    const int t = threadIdx.x;
    const int bc = blockIdx.x >> 3;
    const int kh = (blockIdx.x >> 2) & 1;
    const int q  = blockIdx.x & 3;
    const int p  = q * 256 + t;
    const unsigned short* src = w1b + (size_t)bc * 65536 + p;
    float acc[16];
    #pragma unroll
    for (int k = 0; k < 16; ++k) acc[k] = 0.f;
    #pragma unroll 8
    for (int d = 0; d < 64; ++d) {
        uint32_t u = (uint32_t)src[d * 1024];
        float v = __uint_as_float(u << 16);            // bf16 -> f32
        const float* arow = g_tabs.At + d * 32 + kh * 16;  // wave-uniform -> s_load
        #pragma unroll
        for (int k = 0; k < 16; ++k) acc[k] += arow[k] * v;
    }
    float* dst = out + (size_t)bc * 32768 + (size_t)kh * 16384 + p;
    #pragma unroll
    for (int k = 0; k < 16; ++k) dst[k * 1024] = acc[k];
}

extern "C" void kernel_launch(void* const* d_in, const int* in_sizes, int n_in,
                              void* d_out, int out_size, void* d_ws, size_t ws_size,
                              hipStream_t stream) {
    const float* x = (const float*)d_in[0];
    float* out = (float*)d_out;
    unsigned short* w1b = (unsigned short*)d_ws;   // 16 MiB (bf16)

    k_hw<<<2048, 256, 0, stream>>>(x, w1b);
    k_d<<<1024, 256, 0, stream>>>(w1b, out);
}